// Round 3
// baseline (250.268 us; speedup 1.0000x reference)
//
#include <hip/hip_runtime.h>
#include <stdint.h>

#define NTOK 65536
#define G 4
#define K 1024
#define C 64
#define GC 256
#define R 4                            // 16-row tiles per wave -> 64 rows/wave
#define HALF_CODES 512                 // codes per LDS phase
#define HALF_HALVES (HALF_CODES * C)   // 32768 halves = 64 KB LDS
#define EMB16_BYTES (G * K * C * 2)    // 512 KB in d_ws
#define ROWS_PER_BLOCK 512             // 8 waves * 64 rows
#define LOSS_SCALE (1.5f / ((float)NTOK * (float)GC))

typedef _Float16 half8 __attribute__((ext_vector_type(8)));
typedef float floatx4 __attribute__((ext_vector_type(4)));

__device__ __forceinline__ void gload_lds16(const _Float16* g, _Float16* l) {
    __builtin_amdgcn_global_load_lds(
        (const __attribute__((address_space(1))) uint32_t*)g,
        (__attribute__((address_space(3))) uint32_t*)l, 16, 0, 0);
}

// Negated f16 codebook in d_ws, pre-swizzled into MFMA A-fragment order:
// halves off (within g) = kt_global*1024 + s*512 + lane*8 ; lane = q*16+lr
// holds code = kt_global*16 + lr, halves h = s*32 + q*8 .. +8  (negated!)
// Also zeroes the loss slot.
__global__ __launch_bounds__(256)
void vq_prep(const float* __restrict__ emb, _Float16* __restrict__ emb16,
             float* __restrict__ out) {
    int gid   = blockIdx.x * 256 + threadIdx.x;   // 0..32767
    int lane  = gid & 63;
    int s     = (gid >> 6) & 1;
    int kt    = (gid >> 7) & 7;
    int chunk = (gid >> 10) & 7;
    int g     = gid >> 13;
    int code  = chunk * 128 + kt * 16 + (lane & 15);
    int q     = lane >> 4;
    int h     = s * 32 + q * 8;
    const float* src = emb + ((size_t)(g * K + code)) * C + h;
    floatx4 a = *(const floatx4*)src;
    floatx4 b = *(const floatx4*)(src + 4);
    half8 o;
    o[0] = (_Float16)(-a[0]); o[1] = (_Float16)(-a[1]);
    o[2] = (_Float16)(-a[2]); o[3] = (_Float16)(-a[3]);
    o[4] = (_Float16)(-b[0]); o[5] = (_Float16)(-b[1]);
    o[6] = (_Float16)(-b[2]); o[7] = (_Float16)(-b[3]);
    *(half8*)(emb16 + (size_t)gid * 8) = o;
    if (gid == 0) out[(size_t)NTOK * GC] = 0.0f;   // loss slot
}

// Main: block owns (g, 512 rows) with FULL K via 2-phase LDS restage.
// Barrier-free K-loops, packed (score,code) argmin, single-owner -> plain
// stores to wsbest. Also accumulates sum(z^2) into the loss slot.
__global__ __launch_bounds__(512, 4)
void vq_main(const float* __restrict__ z, const _Float16* __restrict__ emb16,
             unsigned int* __restrict__ wsbest, float* __restrict__ out) {
    __shared__ alignas(16) _Float16 E[HALF_HALVES];   // 64 KB
    __shared__ float red[8];

    const int g    = blockIdx.x & 3;
    const int nb   = blockIdx.x >> 2;                 // 0..127
    const int tid  = threadIdx.x;
    const int wave = tid >> 6;
    const int lane = tid & 63;
    const int q    = lane >> 4;
    const int lr   = lane & 15;
    const int n0   = nb * ROWS_PER_BLOCK + wave * 64;

    const _Float16* esrc = emb16 + (size_t)g * (K * C);

    auto stage = [&](int kh) {
#pragma unroll
        for (int i = 0; i < 8; ++i) {
            const int seg = i * 512 + tid;            // 16-B units, lane-linear
            gload_lds16(esrc + (size_t)kh * HALF_HALVES + seg * 8, &E[seg * 8]);
        }
    };

    stage(0);

    // z fragments: 4 row-tiles x 2 k-steps, f32 -> f16 (NOT negated);
    // accumulate sum(z^2) in f32 from the exact loaded values.
    float zs = 0.0f;
    half8 zf[R][2];
#pragma unroll
    for (int r = 0; r < R; ++r) {
        const float* zp = z + (size_t)(n0 + r * 16 + lr) * GC + g * C + q * 8;
#pragma unroll
        for (int s = 0; s < 2; ++s) {
            floatx4 a = *(const floatx4*)(zp + s * 32);
            floatx4 b = *(const floatx4*)(zp + s * 32 + 4);
            zs += a[0]*a[0] + a[1]*a[1] + a[2]*a[2] + a[3]*a[3]
                + b[0]*b[0] + b[1]*b[1] + b[2]*b[2] + b[3]*b[3];
            half8 h;
            h[0] = (_Float16)a[0]; h[1] = (_Float16)a[1];
            h[2] = (_Float16)a[2]; h[3] = (_Float16)a[3];
            h[4] = (_Float16)b[0]; h[5] = (_Float16)b[1];
            h[6] = (_Float16)b[2]; h[7] = (_Float16)b[3];
            zf[r][s] = h;
        }
    }

    float best[R];
#pragma unroll
    for (int r = 0; r < R; ++r) best[r] = 3.4e38f;
    int vki[4];
#pragma unroll
    for (int j = 0; j < 4; ++j) vki[j] = q * 4 + j;

    const floatx4 BIAS = {0.5f, 0.5f, 0.5f, 0.5f};

    auto ldE = [&](int kt, int s) -> half8 {
        return *(const half8*)(E + kt * 1024 + s * 512 + lane * 8);
    };
    auto body = [&](half8 a0, half8 a1) {
#pragma unroll
        for (int r = 0; r < R; ++r) {
            floatx4 acc = __builtin_amdgcn_mfma_f32_16x16x32_f16(a0, zf[r][0], BIAS, 0, 0, 0);
            acc = __builtin_amdgcn_mfma_f32_16x16x32_f16(a1, zf[r][1], acc, 0, 0, 0);
            uint32_t p0 = (__float_as_uint(acc[0]) & 0xFFFFFC00u) | (uint32_t)vki[0];
            uint32_t p1 = (__float_as_uint(acc[1]) & 0xFFFFFC00u) | (uint32_t)vki[1];
            uint32_t p2 = (__float_as_uint(acc[2]) & 0xFFFFFC00u) | (uint32_t)vki[2];
            uint32_t p3 = (__float_as_uint(acc[3]) & 0xFFFFFC00u) | (uint32_t)vki[3];
            float t = fminf(fminf(__uint_as_float(p0), __uint_as_float(p1)),
                            __uint_as_float(p2));
            best[r] = fminf(fminf(t, __uint_as_float(p3)), best[r]);
        }
#pragma unroll
        for (int j = 0; j < 4; ++j) vki[j] += 16;   // vki continues across phases
    };
    auto kloop = [&]() {   // 32 kt-tiles, barrier-free, depth-2 prefetch
        half8 p0 = ldE(0, 0), p1 = ldE(0, 1);
        half8 q0 = ldE(1, 0), q1 = ldE(1, 1);
#pragma unroll 1
        for (int kt2 = 0; kt2 < 30; kt2 += 2) {
            half8 r0 = ldE(kt2 + 2, 0), r1 = ldE(kt2 + 2, 1);
            half8 s0 = ldE(kt2 + 3, 0), s1 = ldE(kt2 + 3, 1);
            body(p0, p1);
            body(q0, q1);
            p0 = r0; p1 = r1; q0 = s0; q1 = s1;
        }
        body(p0, p1);
        body(q0, q1);
    };

    __syncthreads();        // phase-0 staging complete
    kloop();                // codes 0..511
    __syncthreads();        // all waves done reading E
    stage(1);
    __syncthreads();        // phase-1 staging complete
    kloop();                // codes 512..1023

    // wave reduce across q; packed u32 == lexicographic (score, code) min.
    // Single owner per (row,g): plain store.
#pragma unroll
    for (int r = 0; r < R; ++r) {
        float bv = best[r];
        bv = fminf(bv, __shfl_xor(bv, 16, 64));
        bv = fminf(bv, __shfl_xor(bv, 32, 64));
        if (lane < 16)
            wsbest[(unsigned int)(n0 + r * 16 + lr) * G + g] = __float_as_uint(bv);
    }

    // block-reduce sum(z^2) -> loss slot
#pragma unroll
    for (int off = 1; off < 64; off <<= 1) zs += __shfl_xor(zs, off, 64);
    if (lane == 0) red[wave] = zs;
    __syncthreads();
    if (tid == 0) {
        float s = red[0] + red[1] + red[2] + red[3] +
                  red[4] + red[5] + red[6] + red[7];
        unsafeAtomicAdd(out + (size_t)NTOK * GC, s * LOSS_SCALE);
    }
}

// Epilogue: 8 threads per (row,g), 32 B each. Fully-coalesced out writes
// (wave = 2 KB contiguous), emb gather from L2-resident 1 MB table.
// Loss: |e_win|^2 from gathered values + (2*s_trunc - 1) per unit.
// NO z re-read.
__global__ __launch_bounds__(256)
void vq_epi(const float* __restrict__ emb, const unsigned int* __restrict__ wsbest,
            float* __restrict__ out) {
    __shared__ float wl[4];
    const int tidG = blockIdx.x * 256 + threadIdx.x;   // 0..2097151
    const int unit = tidG >> 3;                        // row*4+g
    const int sub  = tidG & 7;
    const int g    = unit & 3;
    const unsigned int bv = wsbest[unit];
    const int   ki = (int)(bv & 1023u);
    const float st = __uint_as_float(bv & 0xFFFFFC00u);   // trunc(0.5 - e.z)
    const float* ep = emb + ((size_t)(g * K + ki)) * C + sub * 8;
    float*       op = out + (size_t)unit * C + sub * 8;
    floatx4 e0 = *(const floatx4*)ep;
    floatx4 e1 = *(const floatx4*)(ep + 4);
    *(floatx4*)op       = e0;
    *(floatx4*)(op + 4) = e1;
    float lsum = e0[0]*e0[0] + e0[1]*e0[1] + e0[2]*e0[2] + e0[3]*e0[3]
               + e1[0]*e1[0] + e1[1]*e1[1] + e1[2]*e1[2] + e1[3]*e1[3];
    if (sub == 0) lsum += 2.0f * st - 1.0f;            // -2*e.z per unit
#pragma unroll
    for (int off = 1; off < 64; off <<= 1) lsum += __shfl_xor(lsum, off, 64);
    const int wave = threadIdx.x >> 6;
    if ((threadIdx.x & 63) == 0) wl[wave] = lsum;
    __syncthreads();
    if (threadIdx.x == 0)
        unsafeAtomicAdd(out + (size_t)NTOK * GC,
                        (wl[0] + wl[1] + wl[2] + wl[3]) * LOSS_SCALE);
}

extern "C" void kernel_launch(void* const* d_in, const int* in_sizes, int n_in,
                              void* d_out, int out_size, void* d_ws, size_t ws_size,
                              hipStream_t stream) {
    const float* z   = (const float*)d_in[0];
    const float* emb = (const float*)d_in[1];
    float* out = (float*)d_out;
    _Float16* emb16 = (_Float16*)d_ws;
    unsigned int* wsbest = (unsigned int*)((char*)d_ws + EMB16_BYTES);  // 1 MB

    vq_prep<<<dim3(128), dim3(256), 0, stream>>>(emb, emb16, out);
    vq_main<<<dim3((NTOK / ROWS_PER_BLOCK) * G), dim3(512), 0, stream>>>(z, emb16, wsbest, out);
    vq_epi<<<dim3(NTOK * G * 8 / 256), dim3(256), 0, stream>>>(emb, wsbest, out);
}

// Round 4
// 169.149 us; speedup vs baseline: 1.4796x; 1.4796x over previous
//
#include <hip/hip_runtime.h>
#include <stdint.h>

#define NTOK 65536
#define G 4
#define K 1024
#define C 64
#define GC 256
#define NCHUNK 8
#define KCHUNK 128                   // codes per LDS chunk
#define CHUNK_HALVES (KCHUNK * C)    // 8192 halves = 16 KB
#define R 4                          // 16-row tiles per wave -> 64 rows/wave
#define WAVES 2
#define ROWS_PER_BLOCK 128           // 2 waves * 64 rows
#define NBLOCKS ((NTOK / ROWS_PER_BLOCK) * G)   // 2048 -> 2 generations
#define EMB16_BYTES (G * K * C * 2)  // 512 KB in d_ws
#define LOSS_SCALE (1.5f / ((float)NTOK * (float)GC))

typedef _Float16 half8 __attribute__((ext_vector_type(8)));
typedef float floatx4 __attribute__((ext_vector_type(4)));

__device__ __forceinline__ void gload_lds16(const _Float16* g, _Float16* l) {
    __builtin_amdgcn_global_load_lds(
        (const __attribute__((address_space(1))) uint32_t*)g,
        (__attribute__((address_space(3))) uint32_t*)l, 16, 0, 0);
}

// Negated f16 codebook in d_ws, pre-swizzled into MFMA A-fragment order:
// halves off = ((g*8+chunk)*8+kt)*1024 + s*512 + lane*8 ; lane = q*16+lr holds
// code = chunk*128+kt*16+lr, halves h = s*32+q*8 .. +8   (negated!)
__global__ __launch_bounds__(256)
void vq_prep(const float* __restrict__ emb, _Float16* __restrict__ emb16) {
    int gid   = blockIdx.x * 256 + threadIdx.x;   // 0..32767
    int lane  = gid & 63;
    int s     = (gid >> 6) & 1;
    int kt    = (gid >> 7) & 7;
    int chunk = (gid >> 10) & 7;
    int g     = gid >> 13;
    int code  = chunk * KCHUNK + kt * 16 + (lane & 15);
    int q     = lane >> 4;
    int h     = s * 32 + q * 8;
    const float* src = emb + ((size_t)(g * K + code)) * C + h;
    floatx4 a = *(const floatx4*)src;
    floatx4 b = *(const floatx4*)(src + 4);
    half8 o;
    o[0] = (_Float16)(-a[0]); o[1] = (_Float16)(-a[1]);
    o[2] = (_Float16)(-a[2]); o[3] = (_Float16)(-a[3]);
    o[4] = (_Float16)(-b[0]); o[5] = (_Float16)(-b[1]);
    o[6] = (_Float16)(-b[2]); o[7] = (_Float16)(-b[3]);
    *(half8*)(emb16 + (size_t)gid * 8) = o;
}

// Main: R1 structure (chunked double-buffered gload_lds staging, 1 barrier per
// chunk, inline epilogue) + chunk rotation per block (argmin is order-
// independent), 2 generations of blocks, setprio around compute, algebraic
// loss (no z re-read), per-block partial store (no atomics).
__global__ __launch_bounds__(128, 2)
void vq_main(const float* __restrict__ z, const _Float16* __restrict__ emb16,
             const float* __restrict__ emb, float* __restrict__ out,
             float* __restrict__ partial) {
    __shared__ alignas(16) _Float16 Ebuf[2][CHUNK_HALVES];
    __shared__ float red[WAVES];

    const int g    = blockIdx.x & 3;
    const int nb   = blockIdx.x >> 2;            // 0..511
    const int c0   = blockIdx.x & 7;             // chunk rotation offset
    const int wave = threadIdx.x >> 6;
    const int lane = threadIdx.x & 63;
    const int q    = lane >> 4;
    const int lr   = lane & 15;
    const int n0   = nb * ROWS_PER_BLOCK + wave * 64;

    const _Float16* esrc = emb16 + (size_t)g * (K * C);

    auto stage = [&](int chunk, int buf) {
        const _Float16* src = esrc + chunk * CHUNK_HALVES;
#pragma unroll
        for (int i = 0; i < 8; ++i) {
            const int seg = wave * 8 + i;        // 512-half (1 KB) segments
            gload_lds16(src + seg * 512 + lane * 8, &Ebuf[buf][seg * 512]);
        }
    };

    stage(c0, 0);

    // z fragments: 4 row-tiles x 2 k-steps, f32 -> f16 (NOT negated);
    // accumulate sum(z^2) in f32 from the exact loaded values.
    float zs = 0.0f;
    half8 zf[R][2];
#pragma unroll
    for (int r = 0; r < R; ++r) {
        const float* zp = z + (size_t)(n0 + r * 16 + lr) * GC + g * C + q * 8;
#pragma unroll
        for (int s = 0; s < 2; ++s) {
            floatx4 a = *(const floatx4*)(zp + s * 32);
            floatx4 b = *(const floatx4*)(zp + s * 32 + 4);
            zs += a[0]*a[0] + a[1]*a[1] + a[2]*a[2] + a[3]*a[3]
                + b[0]*b[0] + b[1]*b[1] + b[2]*b[2] + b[3]*b[3];
            half8 h;
            h[0] = (_Float16)a[0]; h[1] = (_Float16)a[1];
            h[2] = (_Float16)a[2]; h[3] = (_Float16)a[3];
            h[4] = (_Float16)b[0]; h[5] = (_Float16)b[1];
            h[6] = (_Float16)b[2]; h[7] = (_Float16)b[3];
            zf[r][s] = h;
        }
    }

    // packed argmin state: score' = 0.5 - z.e (positive), low 10 bits = code
    float best[R];
#pragma unroll
    for (int r = 0; r < R; ++r) best[r] = 3.4e38f;

    const floatx4 BIAS = {0.5f, 0.5f, 0.5f, 0.5f};

#pragma unroll 1
    for (int c = 0; c < NCHUNK; ++c) {
        __syncthreads();                         // staging of chunk slot done
        if (c + 1 < NCHUNK) stage((c0 + c + 1) & 7, (c + 1) & 1);
        const _Float16* base = &Ebuf[c & 1][0];
        const int chunk = (c0 + c) & 7;
        int vki[4];
#pragma unroll
        for (int j = 0; j < 4; ++j) vki[j] = chunk * KCHUNK + q * 4 + j;
        __builtin_amdgcn_s_setprio(1);
#pragma unroll
        for (int kt = 0; kt < 8; ++kt) {
            half8 a0 = *(const half8*)(base + kt * 1024 + lane * 8);
            half8 a1 = *(const half8*)(base + kt * 1024 + 512 + lane * 8);
#pragma unroll
            for (int r = 0; r < R; ++r) {
                floatx4 acc = __builtin_amdgcn_mfma_f32_16x16x32_f16(a0, zf[r][0], BIAS, 0, 0, 0);
                acc = __builtin_amdgcn_mfma_f32_16x16x32_f16(a1, zf[r][1], acc, 0, 0, 0);
                uint32_t p0 = (__float_as_uint(acc[0]) & 0xFFFFFC00u) | (uint32_t)vki[0];
                uint32_t p1 = (__float_as_uint(acc[1]) & 0xFFFFFC00u) | (uint32_t)vki[1];
                uint32_t p2 = (__float_as_uint(acc[2]) & 0xFFFFFC00u) | (uint32_t)vki[2];
                uint32_t p3 = (__float_as_uint(acc[3]) & 0xFFFFFC00u) | (uint32_t)vki[3];
                float t = fminf(fminf(__uint_as_float(p0), __uint_as_float(p1)),
                                __uint_as_float(p2));
                best[r] = fminf(fminf(t, __uint_as_float(p3)), best[r]);
            }
#pragma unroll
            for (int j = 0; j < 4; ++j) vki[j] += 16;
        }
        __builtin_amdgcn_s_setprio(0);
    }

    // epilogue: cross-lane argmin (packed compare == lexicographic), gather
    // winner from f32 emb (L2-hot), write out, algebraic loss (NO z re-read):
    // sum(e-z)^2 = sum e^2 + (2*s_trunc - 1) per unit + sum z^2.
    float lsum = zs;
#pragma unroll
    for (int r = 0; r < R; ++r) {
        float bv = best[r];
        bv = fminf(bv, __shfl_xor(bv, 16, 64));
        bv = fminf(bv, __shfl_xor(bv, 32, 64));
        const int   ki = (int)(__float_as_uint(bv) & 1023u);
        const float st = __uint_as_float(__float_as_uint(bv) & 0xFFFFFC00u);
        const int row = n0 + r * 16 + lr;
        const float* ep = emb + ((size_t)(g * K + ki)) * C + q * 16;
        float*       op = out + (size_t)row * GC + g * C + q * 16;
#pragma unroll
        for (int u = 0; u < 4; ++u) {
            floatx4 e = *(const floatx4*)(ep + u * 4);
            *(floatx4*)(op + u * 4) = e;
            lsum += e[0]*e[0] + e[1]*e[1] + e[2]*e[2] + e[3]*e[3];
        }
        if (q == 0) lsum += 2.0f * st - 1.0f;    // -2*e.z for this (row,g)
    }
#pragma unroll
    for (int off = 1; off < 64; off <<= 1) lsum += __shfl_xor(lsum, off, 64);
    if (lane == 0) red[wave] = lsum;
    __syncthreads();
    if (threadIdx.x == 0) partial[blockIdx.x] = red[0] + red[1];
}

__global__ __launch_bounds__(256)
void vq_fin(const float* __restrict__ partial, float* __restrict__ out) {
    __shared__ float wl[4];
    float s = 0.0f;
#pragma unroll
    for (int i = 0; i < 8; ++i) s += partial[threadIdx.x + i * 256];
#pragma unroll
    for (int off = 1; off < 64; off <<= 1) s += __shfl_xor(s, off, 64);
    const int wave = threadIdx.x >> 6;
    if ((threadIdx.x & 63) == 0) wl[wave] = s;
    __syncthreads();
    if (threadIdx.x == 0)
        out[(size_t)NTOK * GC] = (wl[0] + wl[1] + wl[2] + wl[3]) * LOSS_SCALE;
}

extern "C" void kernel_launch(void* const* d_in, const int* in_sizes, int n_in,
                              void* d_out, int out_size, void* d_ws, size_t ws_size,
                              hipStream_t stream) {
    const float* z   = (const float*)d_in[0];
    const float* emb = (const float*)d_in[1];
    float* out = (float*)d_out;
    _Float16* emb16 = (_Float16*)d_ws;
    float* partial  = (float*)((char*)d_ws + EMB16_BYTES);   // 8 KB

    vq_prep<<<dim3(128), dim3(256), 0, stream>>>(emb, emb16);
    vq_main<<<dim3(NBLOCKS), dim3(128), 0, stream>>>(z, emb16, emb, out, partial);
    vq_fin<<<dim3(1), dim3(256), 0, stream>>>(partial, out);
}

// Round 6
// 150.521 us; speedup vs baseline: 1.6627x; 1.1238x over previous
//
#include <hip/hip_runtime.h>
#include <stdint.h>

#define NTOK 65536
#define G 4
#define K 1024
#define C 64
#define GC 256
#define NCHUNK 16
#define KCHUNK 64                    // codes per LDS chunk
#define CHUNK_HALVES (KCHUNK * C)    // 4096 halves = 8 KB
#define NBUF 4                       // depth-3 pipeline
#define R 4                          // 16-row tiles per wave -> 64 rows/wave
#define WAVES 4
#define ROWS_PER_BLOCK 256           // 4 waves * 64 rows
#define NBLOCKS ((NTOK / ROWS_PER_BLOCK) * G)   // 1024 -> all resident
#define EMB16_BYTES (G * K * C * 2)  // 512 KB in d_ws
#define LOSS_SCALE (1.5f / ((float)NTOK * (float)GC))

typedef _Float16 half8 __attribute__((ext_vector_type(8)));
typedef float floatx4 __attribute__((ext_vector_type(4)));

__device__ __forceinline__ void gload_lds16(const _Float16* g, _Float16* l) {
    __builtin_amdgcn_global_load_lds(
        (const __attribute__((address_space(1))) uint32_t*)g,
        (__attribute__((address_space(3))) uint32_t*)l, 16, 0, 0);
}

// Negated f16 codebook in d_ws, pre-swizzled into MFMA A-fragment order:
// halves off = ((g*8+chunk128)*8+kt)*1024 + s*512 + lane*8 ; lane = q*16+lr
// holds code = chunk128*128+kt*16+lr, halves h = s*32+q*8 .. +8  (negated!)
// A 64-code chunk64 c is the contiguous 8 KB at  g*65536 + c*4096 halves.
__global__ __launch_bounds__(256)
void vq_prep(const float* __restrict__ emb, _Float16* __restrict__ emb16) {
    int gid   = blockIdx.x * 256 + threadIdx.x;   // 0..32767
    int lane  = gid & 63;
    int s     = (gid >> 6) & 1;
    int kt    = (gid >> 7) & 7;
    int chunk = (gid >> 10) & 7;
    int g     = gid >> 13;
    int code  = chunk * 128 + kt * 16 + (lane & 15);
    int q     = lane >> 4;
    int h     = s * 32 + q * 8;
    const float* src = emb + ((size_t)(g * K + code)) * C + h;
    floatx4 a = *(const floatx4*)src;
    floatx4 b = *(const floatx4*)(src + 4);
    half8 o;
    o[0] = (_Float16)(-a[0]); o[1] = (_Float16)(-a[1]);
    o[2] = (_Float16)(-a[2]); o[3] = (_Float16)(-a[3]);
    o[4] = (_Float16)(-b[0]); o[5] = (_Float16)(-b[1]);
    o[6] = (_Float16)(-b[2]); o[7] = (_Float16)(-b[3]);
    *(half8*)(emb16 + (size_t)gid * 8) = o;
}

// Main: T3+T4 counted-vmcnt pipeline. 16 chunks x 64 codes, 4 LDS buffers,
// loads for chunks c+1..c+2 stay IN FLIGHT across the per-chunk s_barrier
// (never vmcnt(0) in steady state). Raw s_barrier (no compiler drain),
// sched_barrier fences pin ordering. Packed (score,code) argmin, algebraic
// loss, per-block partial store.
__global__ __launch_bounds__(256, 4)
void vq_main(const float* __restrict__ z, const _Float16* __restrict__ emb16,
             const float* __restrict__ emb, float* __restrict__ out,
             float* __restrict__ partial) {
    __shared__ alignas(16) _Float16 Ebuf[NBUF][CHUNK_HALVES];   // 32 KB
    __shared__ float red[WAVES];

    const int g    = blockIdx.x & 3;
    const int nb   = blockIdx.x >> 2;            // 0..255
    const int c0   = nb & 15;                    // chunk rotation offset
    const int tid  = threadIdx.x;
    const int wave = tid >> 6;
    const int lane = tid & 63;
    const int q    = lane >> 4;
    const int lr   = lane & 15;
    const int n0   = nb * ROWS_PER_BLOCK + wave * 64;

    const _Float16* esrc = emb16 + (size_t)g * (K * C);

    // 8 KB chunk = 512 x 16B units; 256 threads -> 2 gload_lds per thread
    // (= 2 per wave in vmcnt terms; dest is wave-uniform-base + lane*16).
    auto stage = [&](int chunk, int buf) {
        const _Float16* src = esrc + chunk * CHUNK_HALVES;
        _Float16* dst = &Ebuf[buf][0];
#pragma unroll
        for (int i = 0; i < 2; ++i) {
            const int seg = i * 256 + tid;
            gload_lds16(src + seg * 8, dst + seg * 8);
        }
    };

    stage(c0, 0);
    stage((c0 + 1) & 15, 1);
    stage((c0 + 2) & 15, 2);

    // z fragments: 4 row-tiles x 2 k-steps, f32 -> f16 (NOT negated);
    // accumulate sum(z^2) in f32 from the exact loaded values.
    float zs = 0.0f;
    half8 zf[R][2];
#pragma unroll
    for (int r = 0; r < R; ++r) {
        const float* zp = z + (size_t)(n0 + r * 16 + lr) * GC + g * C + q * 8;
#pragma unroll
        for (int s = 0; s < 2; ++s) {
            floatx4 a = *(const floatx4*)(zp + s * 32);
            floatx4 b = *(const floatx4*)(zp + s * 32 + 4);
            zs += a[0]*a[0] + a[1]*a[1] + a[2]*a[2] + a[3]*a[3]
                + b[0]*b[0] + b[1]*b[1] + b[2]*b[2] + b[3]*b[3];
            half8 h;
            h[0] = (_Float16)a[0]; h[1] = (_Float16)a[1];
            h[2] = (_Float16)a[2]; h[3] = (_Float16)a[3];
            h[4] = (_Float16)b[0]; h[5] = (_Float16)b[1];
            h[6] = (_Float16)b[2]; h[7] = (_Float16)b[3];
            zf[r][s] = h;
        }
    }

    float best[R];
#pragma unroll
    for (int r = 0; r < R; ++r) best[r] = 3.4e38f;

    const floatx4 BIAS = {0.5f, 0.5f, 0.5f, 0.5f};

    // establish exact vmcnt baseline 0 before the counted pipeline
    asm volatile("s_waitcnt vmcnt(0)" ::: "memory");
    __builtin_amdgcn_sched_barrier(0);

#pragma unroll 1
    for (int c = 0; c < NCHUNK; ++c) {
        // counted wait: chunk c's 2 loads done; chunks c+1,c+2 (4 loads)
        // remain in flight. Peel counts for the last two chunks.
        if (c <= NCHUNK - 3)      { asm volatile("s_waitcnt vmcnt(4)" ::: "memory"); }
        else if (c == NCHUNK - 2) { asm volatile("s_waitcnt vmcnt(2)" ::: "memory"); }
        else                      { asm volatile("s_waitcnt vmcnt(0)" ::: "memory"); }
        __builtin_amdgcn_s_barrier();          // all waves done with chunk c-1
        __builtin_amdgcn_sched_barrier(0);     // pin: no LDS op crosses up
        if (c + 3 < NCHUNK) stage((c0 + c + 3) & 15, (c + 3) & 3);

        const _Float16* base = &Ebuf[c & 3][0];
        const int ch = (c0 + c) & 15;
        int vki[4];
#pragma unroll
        for (int j = 0; j < 4; ++j) vki[j] = ch * KCHUNK + q * 4 + j;
#pragma unroll
        for (int ktl = 0; ktl < 4; ++ktl) {
            half8 a0 = *(const half8*)(base + ktl * 1024 + lane * 8);
            half8 a1 = *(const half8*)(base + ktl * 1024 + 512 + lane * 8);
            __builtin_amdgcn_s_setprio(1);
#pragma unroll
            for (int r = 0; r < R; ++r) {
                floatx4 acc = __builtin_amdgcn_mfma_f32_16x16x32_f16(a0, zf[r][0], BIAS, 0, 0, 0);
                acc = __builtin_amdgcn_mfma_f32_16x16x32_f16(a1, zf[r][1], acc, 0, 0, 0);
                uint32_t p0 = (__float_as_uint(acc[0]) & 0xFFFFFC00u) | (uint32_t)vki[0];
                uint32_t p1 = (__float_as_uint(acc[1]) & 0xFFFFFC00u) | (uint32_t)vki[1];
                uint32_t p2 = (__float_as_uint(acc[2]) & 0xFFFFFC00u) | (uint32_t)vki[2];
                uint32_t p3 = (__float_as_uint(acc[3]) & 0xFFFFFC00u) | (uint32_t)vki[3];
                float t = fminf(fminf(__uint_as_float(p0), __uint_as_float(p1)),
                                __uint_as_float(p2));
                best[r] = fminf(fminf(t, __uint_as_float(p3)), best[r]);
            }
            __builtin_amdgcn_s_setprio(0);
#pragma unroll
            for (int j = 0; j < 4; ++j) vki[j] += 16;
        }
    }

    // epilogue: cross-lane argmin (packed compare == lexicographic), gather
    // winner from f32 emb (L2-hot), write out, algebraic loss (NO z re-read):
    // sum(e-z)^2 = sum e^2 + (2*s_trunc - 1) per unit + sum z^2.
    float lsum = zs;
#pragma unroll
    for (int r = 0; r < R; ++r) {
        float bv = best[r];
        bv = fminf(bv, __shfl_xor(bv, 16, 64));
        bv = fminf(bv, __shfl_xor(bv, 32, 64));
        const int   ki = (int)(__float_as_uint(bv) & 1023u);
        const float st = __uint_as_float(__float_as_uint(bv) & 0xFFFFFC00u);
        const int row = n0 + r * 16 + lr;
        const float* ep = emb + ((size_t)(g * K + ki)) * C + q * 16;
        float*       op = out + (size_t)row * GC + g * C + q * 16;
#pragma unroll
        for (int u = 0; u < 4; ++u) {
            floatx4 e = *(const floatx4*)(ep + u * 4);
            *(floatx4*)(op + u * 4) = e;
            lsum += e[0]*e[0] + e[1]*e[1] + e[2]*e[2] + e[3]*e[3];
        }
        if (q == 0) lsum += 2.0f * st - 1.0f;    // -2*e.z for this (row,g)
    }
#pragma unroll
    for (int off = 1; off < 64; off <<= 1) lsum += __shfl_xor(lsum, off, 64);
    if (lane == 0) red[wave] = lsum;
    __syncthreads();
    if (tid == 0)
        partial[blockIdx.x] = red[0] + red[1] + red[2] + red[3];
}

__global__ __launch_bounds__(256)
void vq_fin(const float* __restrict__ partial, float* __restrict__ out) {
    __shared__ float wl[4];
    float s = 0.0f;
#pragma unroll
    for (int i = 0; i < 4; ++i) s += partial[threadIdx.x + i * 256];
#pragma unroll
    for (int off = 1; off < 64; off <<= 1) s += __shfl_xor(s, off, 64);
    const int wave = threadIdx.x >> 6;
    if ((threadIdx.x & 63) == 0) wl[wave] = s;
    __syncthreads();
    if (threadIdx.x == 0)
        out[(size_t)NTOK * GC] = (wl[0] + wl[1] + wl[2] + wl[3]) * LOSS_SCALE;
}

extern "C" void kernel_launch(void* const* d_in, const int* in_sizes, int n_in,
                              void* d_out, int out_size, void* d_ws, size_t ws_size,
                              hipStream_t stream) {
    const float* z   = (const float*)d_in[0];
    const float* emb = (const float*)d_in[1];
    float* out = (float*)d_out;
    _Float16* emb16 = (_Float16*)d_ws;
    float* partial  = (float*)((char*)d_ws + EMB16_BYTES);   // 4 KB

    vq_prep<<<dim3(128), dim3(256), 0, stream>>>(emb, emb16);
    vq_main<<<dim3(NBLOCKS), dim3(256), 0, stream>>>(z, emb16, emb, out, partial);
    vq_fin<<<dim3(1), dim3(256), 0, stream>>>(partial, out);
}